// Round 7
// baseline (108.762 us; speedup 1.0000x reference)
//
#include <hip/hip_runtime.h>

// Problem constants (match reference)
#define NB 32768   // batch rows
#define NF 256     // features
#define NH 8       // hidden dim
#define ROWS_PER_BLOCK 32
#define CH 8       // prefetch chunk (rows)

// One thread per feature; 96 MLP params in registers (loaded first — the only
// exposed latency). Row inputs prefetched in software-pipelined chunks of 8.
// KEY CHANGE vs round 5: the compute loop issues NO global stores — s goes to
// LDS only, so the vmcnt queue contains only x-loads and every chunk's
// s_waitcnt waits on load arrival, never on store retirement. After one
// barrier, a store phase reads sred rows as float4 (2-way LDS, free) and
// writes out_w as coalesced dwordx4 AND computes the row-sum butterfly.
// All global stores are fire-and-forget at the end of the kernel.
__global__ __launch_bounds__(256, 3) void NAM_49314814493074_kernel(
    const float* __restrict__ input,   // [B, F]
    const float* __restrict__ W1,      // [F, 8]
    const float* __restrict__ b1,      // [F, 8]
    const float* __restrict__ W2,      // [F, 8, 8]
    const float* __restrict__ b2,      // [F, 8]
    const float* __restrict__ W3,      // [F, 8]
    float* __restrict__ out_sum,       // [B]
    float* __restrict__ out_w)         // [B, F]
{
    __shared__ float sred[ROWS_PER_BLOCK][NF];   // 32 KB

    const int f = threadIdx.x;                  // feature index 0..255
    const int row0 = blockIdx.x * ROWS_PER_BLOCK;

    // ---- params first: the only loads whose latency is ever exposed ----
    float w1[NH], bb1[NH], bb2[NH], w3[NH];
    float w2[NH][NH];
    {
        const float4* p1  = reinterpret_cast<const float4*>(W1 + (size_t)f * NH);
        const float4* pb1 = reinterpret_cast<const float4*>(b1 + (size_t)f * NH);
        const float4* pb2 = reinterpret_cast<const float4*>(b2 + (size_t)f * NH);
        const float4* p3  = reinterpret_cast<const float4*>(W3 + (size_t)f * NH);
        float4 a, b;
        a = p1[0]; b = p1[1];
        w1[0]=a.x; w1[1]=a.y; w1[2]=a.z; w1[3]=a.w; w1[4]=b.x; w1[5]=b.y; w1[6]=b.z; w1[7]=b.w;
        a = pb1[0]; b = pb1[1];
        bb1[0]=a.x; bb1[1]=a.y; bb1[2]=a.z; bb1[3]=a.w; bb1[4]=b.x; bb1[5]=b.y; bb1[6]=b.z; bb1[7]=b.w;
        a = pb2[0]; b = pb2[1];
        bb2[0]=a.x; bb2[1]=a.y; bb2[2]=a.z; bb2[3]=a.w; bb2[4]=b.x; bb2[5]=b.y; bb2[6]=b.z; bb2[7]=b.w;
        a = p3[0]; b = p3[1];
        w3[0]=a.x; w3[1]=a.y; w3[2]=a.z; w3[3]=a.w; w3[4]=b.x; w3[5]=b.y; w3[6]=b.z; w3[7]=b.w;

        const float4* p2 = reinterpret_cast<const float4*>(W2 + (size_t)f * NH * NH);
        #pragma unroll
        for (int h = 0; h < NH; ++h) {
            float4 c0 = p2[h * 2 + 0];
            float4 c1 = p2[h * 2 + 1];
            w2[h][0]=c0.x; w2[h][1]=c0.y; w2[h][2]=c0.z; w2[h][3]=c0.w;
            w2[h][4]=c1.x; w2[h][5]=c1.y; w2[h][6]=c1.z; w2[h][7]=c1.w;
        }
    }

    const float* xin = input + (size_t)row0 * NF + f;

    float xA[CH], xB[CH];

    // per-row MLP: ~96 VALU ops, result goes to LDS ONLY (no global store).
    auto compute8 = [&](float (&xb)[CH], int r0) {
        #pragma unroll
        for (int i = 0; i < CH; ++i) {
            const float x = xb[i];
            float h1[NH];
            #pragma unroll
            for (int h = 0; h < NH; ++h)
                h1[h] = fmaxf(fmaf(x, w1[h], bb1[h]), 0.0f);

            float acc[NH];
            #pragma unroll
            for (int k = 0; k < NH; ++k)       // fold init into h=0 FMA
                acc[k] = fmaf(h1[0], w2[0][k], bb2[k]);
            #pragma unroll
            for (int h = 1; h < NH; ++h) {
                #pragma unroll
                for (int k = 0; k < NH; ++k)
                    acc[k] = fmaf(h1[h], w2[h][k], acc[k]);
            }

            float s = 0.0f;
            #pragma unroll
            for (int k = 0; k < NH; ++k)
                s = fmaf(fmaxf(acc[k], 0.0f), w3[k], s);

            sred[r0 + i][f] = s;
        }
    };

    // ---- software pipeline: load chunk c+1 while computing chunk c ----
    #pragma unroll
    for (int i = 0; i < CH; ++i) xA[i] = xin[(size_t)i * NF];

    #pragma unroll
    for (int i = 0; i < CH; ++i) xB[i] = xin[(size_t)(CH + i) * NF];
    compute8(xA, 0);

    #pragma unroll
    for (int i = 0; i < CH; ++i) xA[i] = xin[(size_t)(2 * CH + i) * NF];
    compute8(xB, CH);

    #pragma unroll
    for (int i = 0; i < CH; ++i) xB[i] = xin[(size_t)(3 * CH + i) * NF];
    compute8(xA, 2 * CH);

    compute8(xB, 3 * CH);

    __syncthreads();

    // ---- store + reduce phase: wave w handles rows [8w, 8w+8) ----
    // ds_read_b128 per row (2-way, conflict-free), coalesced dwordx4 store of
    // out_w, and the row-sum butterfly from the same registers.
    const int wave = threadIdx.x >> 6;
    const int lane = threadIdx.x & 63;
    #pragma unroll
    for (int rr = 0; rr < ROWS_PER_BLOCK / 4; ++rr) {
        const int r = wave * (ROWS_PER_BLOCK / 4) + rr;
        const float4 q = reinterpret_cast<const float4*>(&sred[r][0])[lane];
        reinterpret_cast<float4*>(out_w + (size_t)(row0 + r) * NF)[lane] = q;
        float v = q.x + q.y + q.z + q.w;
        #pragma unroll
        for (int off = 32; off > 0; off >>= 1)
            v += __shfl_xor(v, off, 64);
        if (lane == 0)
            out_sum[row0 + r] = v;
    }
}

extern "C" void kernel_launch(void* const* d_in, const int* in_sizes, int n_in,
                              void* d_out, int out_size, void* d_ws, size_t ws_size,
                              hipStream_t stream) {
    const float* input = (const float*)d_in[0];
    const float* W1    = (const float*)d_in[1];
    const float* b1    = (const float*)d_in[2];
    const float* W2    = (const float*)d_in[3];
    const float* b2    = (const float*)d_in[4];
    const float* W3    = (const float*)d_in[5];

    float* out = (float*)d_out;          // [B] sums, then [B,F] w
    float* out_sum = out;
    float* out_w   = out + NB;

    dim3 grid(NB / ROWS_PER_BLOCK);      // 1024 blocks
    dim3 block(NF);                      // 256 threads = 1 per feature
    NAM_49314814493074_kernel<<<grid, block, 0, stream>>>(
        input, W1, b1, W2, b2, W3, out_sum, out_w);
}